// Round 17
// baseline (90.338 us; speedup 1.0000x reference)
//
#include <hip/hip_runtime.h>

#define IMG_B 256
#define IMG_H 224
#define IMG_W 224
#define HWPIX 50176

// exact IEEE f32 ops, no contraction, matching numpy's elementwise semantics
#define FA(a,b) __fadd_rn((a),(b))
#define FM(a,b) __fmul_rn((a),(b))
#define FS(a,b) __fsub_rn((a),(b))
#define FD(a,b) __fdiv_rn((a),(b))

// python-float scalars cast to f32 exactly as numpy weak-scalar promotion does
__device__ __forceinline__ float VBF()   { return (float)(9.0/30.0*(1.9-0.1)+0.1); }
__device__ __forceinline__ float OMVBF() { return (float)(1.0 - (9.0/30.0*(1.9-0.1)+0.1)); }
__device__ __forceinline__ float VSF()   { return (float)(9.0/30.0*1.0); }

// exact blur fold (9 terms, raster order) + y1 blend, for 4 pixels
__device__ __forceinline__ void y1_from_rows(const float* yU, const float* yC,
                                             const float* yD, float* y1o) {
    const float WN = 1.0f / 13.0f, WC = 5.0f / 13.0f;
#pragma unroll
    for (int mm = 0; mm < 4; ++mm) {
        float acc = 0.0f;
        acc = FA(acc, FM(WN, yU[mm + 0]));
        acc = FA(acc, FM(WN, yU[mm + 1]));
        acc = FA(acc, FM(WN, yU[mm + 2]));
        acc = FA(acc, FM(WN, yC[mm + 0]));
        acc = FA(acc, FM(WC, yC[mm + 1]));
        acc = FA(acc, FM(WN, yC[mm + 2]));
        acc = FA(acc, FM(WN, yD[mm + 0]));
        acc = FA(acc, FM(WN, yD[mm + 1]));
        acc = FA(acc, FM(WN, yD[mm + 2]));
        y1o[mm] = FA(FM(yC[mm + 1], VBF()), FM(acc, OMVBF()));
    }
}

// prefetch raw x float4s for the 896 staged quads (rows r0-1..r0+14) into regs (kB)
__device__ __forceinline__ void stage_load(const float* __restrict__ xc, int r0,
                                           int t, float4* pf) {
#pragma unroll
    for (int u = 0; u < 4; ++u) {
        const int idx = t + 256 * u;
        float4 v = make_float4(0.f, 0.f, 0.f, 0.f);
        if (idx < 896) {
            const int row = idx / 56, c4 = (idx % 56) * 4;
            const int gi = r0 - 1 + row;
            if (gi >= 0 && gi < IMG_H)
                v = *(const float4*)(xc + (size_t)gi * IMG_W + c4);
        }
        pf[u] = v;
    }
}

// write y = s*x+m to LDS (pitch P dwords) from prefetched regs; pad rows -> 0 (kB)
__device__ __forceinline__ void stage_write(float s, float m, int r0, int t,
                                            const float4* pf, float* __restrict__ Y,
                                            int P) {
#pragma unroll
    for (int u = 0; u < 4; ++u) {
        const int idx = t + 256 * u;
        if (idx < 896) {
            const int row = idx / 56, c4 = (idx % 56) * 4;
            const int gi = r0 - 1 + row;
            float4 w;
            if (gi >= 0 && gi < IMG_H) {
                w.x = FA(FM(pf[u].x, s), m);
                w.y = FA(FM(pf[u].y, s), m);
                w.z = FA(FM(pf[u].z, s), m);
                w.w = FA(FM(pf[u].w, s), m);
            } else {
                w.x = w.y = w.z = w.w = 0.0f;
            }
            *(float4*)(&Y[row * P + c4]) = w;
        }
    }
}

// 6 y-taps from LDS (kB only; pitch 224): aligned float4 reads
__device__ __forceinline__ void lds_y6(const float* __restrict__ r, int j, float* y6) {
    const float4 vC = *(const float4*)(r + j);
    const float4 vL = *(const float4*)(r + (j > 0 ? j - 4 : 0));
    const float4 vR = *(const float4*)(r + (j + 4 < IMG_W ? j + 4 : IMG_W - 4));
    y6[0] = (j > 0) ? vL.w : 0.0f;
    y6[1] = vC.x; y6[2] = vC.y; y6[3] = vC.z; y6[4] = vC.w;
    y6[5] = (j + 4 < IMG_W) ? vR.x : 0.0f;
}

// ---- Kernel A1: one block = one 3136-px chunk (14 rows) = 32 aligned leaves.
// NO-STAGE SWEEP: wave w = rowgroup (rows 4,4,3,3); lane = column-quad (56 of
// 64; lanes 56-63 clamped duplicates, masked on write). Vertical window slides
// in registers; horizontal taps via intra-wave shfl; gray folded at load.
// LDS holds only G2/CH/LS (14.4 KB). Exact chains / leaf sums / subtree root.
__global__ __launch_bounds__(256, 4) void kA1(const float* __restrict__ x,
                                              const float* __restrict__ mean_,
                                              const float* __restrict__ std_,
                                              float* __restrict__ part) {
    const int ck = blockIdx.x & 15, b = blockIdx.x >> 4;
    const int t = threadIdx.x;
    const int r0 = ck * 14;

    __shared__ float SM[3616];        // 14464 B: G2[0,3328) CH[3328,3584) LS[3584,3616)
    float* G2 = SM;
    float* CH = SM + 3328;
    float* LS = SM + 3584;

    const int w  = t >> 6;            // wave = rowgroup
    const int l  = t & 63;
    const int cq = (l < 56) ? l : 55; // clamped column-quad
    const int jd = cq * 4;
    const bool lanev = (l < 56);
    const int rcount = (w < 2) ? 4 : 3;                      // rows 4,4,3,3
    const int rstart = (w < 2) ? w * 4 : 8 + (w - 2) * 3;    // 0,4,8,11

    const float s0 = std_[0], s1 = std_[1], s2 = std_[2];
    const float m0 = mean_[0], m1 = mean_[1], m2 = mean_[2];
    const float C0 = 0.299f, C1 = 0.587f, C2 = 0.114f;
    const float* xb = x + (size_t)b * 3 * HWPIX;

    // exact gray of y = s*x+m, per scalar
#define GRAY1(a0v, a1v, a2v)                                              \
    FA(FA(FM(C0, FA(FM(a0v, s0), m0)), FM(C1, FA(FM(a1v, s1), m1))),      \
       FM(C2, FA(FM(a2v, s2), m2)))

    // load gray row n (sweep row index; global row r0+rstart+n-1) + h-taps
#define LOADG(GV, LGV, RGV, n) do {                                       \
        const int gr = r0 + rstart + (n) - 1;                             \
        float4 gg = make_float4(0.f, 0.f, 0.f, 0.f);                      \
        if (gr >= 0 && gr < IMG_H) {                                      \
            const float* p = xb + (size_t)gr * IMG_W + jd;                \
            const float4 qa = *(const float4*)(p);                        \
            const float4 qb = *(const float4*)(p + HWPIX);                \
            const float4 qc = *(const float4*)(p + 2 * HWPIX);            \
            gg.x = GRAY1(qa.x, qb.x, qc.x);                               \
            gg.y = GRAY1(qa.y, qb.y, qc.y);                               \
            gg.z = GRAY1(qa.z, qb.z, qc.z);                               \
            gg.w = GRAY1(qa.w, qb.w, qc.w);                               \
        }                                                                 \
        GV  = gg;                                                         \
        LGV = __shfl_up(gg.w, 1, 64);                                     \
        RGV = __shfl_down(gg.x, 1, 64);                                   \
    } while (0)

#define FILL6(y6, V, LWv, RWv) do {                                       \
        y6[0] = (cq > 0) ? LWv : 0.0f;                                    \
        y6[1] = V.x; y6[2] = V.y; y6[3] = V.z; y6[4] = V.w;               \
        y6[5] = (cq < 55) ? RWv : 0.0f;                                   \
    } while (0)

    float4 gacc[4];
    {
        float4 g0v, g1v, g2v;
        float la0, la1, la2, ra0, ra1, ra2;
        LOADG(g0v, la0, ra0, 0);
        LOADG(g1v, la1, ra1, 1);
#pragma unroll
        for (int k = 0; k < 4; ++k) {
            if (k < rcount) {
                LOADG(g2v, la2, ra2, k + 2);
                float yU[6], yC[6], yD[6], y1g[4];
                FILL6(yU, g0v, la0, ra0);
                FILL6(yC, g1v, la1, ra1);
                FILL6(yD, g2v, la2, ra2);
                y1_from_rows(yU, yC, yD, y1g);
                gacc[k].x = y1g[0]; gacc[k].y = y1g[1];
                gacc[k].z = y1g[2]; gacc[k].w = y1g[3];
                g0v = g1v; la0 = la1; ra0 = ra1;
                g1v = g2v; la1 = la2; ra1 = ra2;
            }
        }
    }

    // ---- write gray(y1) into leaf-padded G2 ----
    if (lanev) {
#pragma unroll
        for (int k = 0; k < 4; ++k) {
            if (k < rcount) {
                const int pl = (rstart + k) * IMG_W + jd;
                const int grp = pl / 392;
                const int rem = pl - grp * 392;
                int li = rem / 96; if (li > 3) li = 3;
                const int o = rem - 96 * li;
                *(float4*)(&G2[(grp * 4 + li) * 104 + o]) = gacc[k];
            }
        }
    }
    __syncthreads();

    // ---- 8 chains per leaf (exact numpy base case) ----
    {
        const int leaf = t >> 3, e = t & 7;
        const int base = leaf * 104 + e;
        const int nk = ((leaf & 3) == 3) ? 13 : 12;
        float r = G2[base];
        for (int k = 1; k < nk; ++k) r = FA(r, G2[base + 8 * k]);
        CH[t] = r;   // t == leaf*8+e
    }
    __syncthreads();

    if (t < 32) {
        const float* c8 = &CH[t * 8];
        LS[t] = FA(FA(FA(c8[0], c8[1]), FA(c8[2], c8[3])),
                   FA(FA(c8[4], c8[5]), FA(c8[6], c8[7])));
    }
    __syncthreads();

    if (t == 0) {
        float v[32];
#pragma unroll
        for (int k = 0; k < 32; ++k) v[k] = LS[k];
        for (int n = 16; n >= 1; n >>= 1)
            for (int k = 0; k < n; ++k) v[k] = FA(v[2 * k], v[2 * k + 1]);
        part[blockIdx.x] = v[0];
    }
#undef LOADG
#undef FILL6
#undef GRAY1
}

// ---- Kernel B: one block = one 14-row chunk of one (b,c); staged (UNCHANGED,
// bit-exact per-channel path) ----
__global__ __launch_bounds__(256) void kB(const float* __restrict__ x,
                                          const float* __restrict__ mean_,
                                          const float* __restrict__ std_,
                                          const float* __restrict__ part,
                                          float* __restrict__ out) {
    const int ck = blockIdx.x, c = blockIdx.y, b = blockIdx.z;
    const int t = threadIdx.x;
    const int r0 = ck * 14;

    __shared__ float Y[16 * IMG_W];
    __shared__ float gsh;

    const float s = std_[c], m = mean_[c];
    float4 pf[4];
    stage_load(x + (size_t)(b * 3 + c) * HWPIX, r0, t, pf);
    stage_write(s, m, r0, t, pf, Y, IMG_W);

    if (t == 0) {
        // exact 4-level fold of the 16 chunk roots, / 50176
        float v[16];
#pragma unroll
        for (int k = 0; k < 16; ++k) v[k] = part[b * 16 + k];
#pragma unroll
        for (int n = 8; n >= 1; n >>= 1)
#pragma unroll
            for (int k = 0; k < 8; ++k)
                if (k < n) v[k] = FA(v[2 * k], v[2 * k + 1]);
        gsh = FD(v[0], 50176.0f);
    }
    __syncthreads();
    const float g = gsh;

    float* oc = out + (size_t)(b * 3 + c) * HWPIX + (size_t)r0 * IMG_W;

    for (int qi = t; qi < 784; qi += 256) {
        const int lr = qi / 56 + 1, j = (qi % 56) * 4;
        float yU[6], yC[6], yD[6], y1[4];
        lds_y6(&Y[(lr - 1) * IMG_W], j, yU);
        lds_y6(&Y[lr * IMG_W],       j, yC);
        lds_y6(&Y[(lr + 1) * IMG_W], j, yD);
        y1_from_rows(yU, yC, yD, y1);

        float ov[4];
#pragma unroll
        for (int mm = 0; mm < 4; ++mm) {
            const float y2 = FA(FM(y1[mm], VBF()), FM(g, OMVBF()));
            const float y3 = FM(y2, VBF());
            const float y4 = (y3 < VSF()) ? y3 : FS(1.0f, y3);
            ov[mm] = FD(FS(y4, m), s);
        }
        float4 o;
        o.x = ov[0]; o.y = ov[1]; o.z = ov[2]; o.w = ov[3];
        *(float4*)(oc + (size_t)(lr - 1) * IMG_W + j) = o;
    }
}

extern "C" void kernel_launch(void* const* d_in, const int* in_sizes, int n_in,
                              void* d_out, int out_size, void* d_ws, size_t ws_size,
                              hipStream_t stream) {
    const float* x     = (const float*)d_in[0];
    const float* mean_ = (const float*)d_in[1];
    const float* std_  = (const float*)d_in[2];
    float* out = (float*)d_out;

    float* part = (float*)d_ws;   // 4096 f32 (16 chunk roots x 256 images)

    kA1<<<IMG_B * 16, 256, 0, stream>>>(x, mean_, std_, part);

    dim3 gridB(16, 3, IMG_B);
    kB<<<gridB, 256, 0, stream>>>(x, mean_, std_, part, out);
}

// Round 18
// 82.935 us; speedup vs baseline: 1.0893x; 1.0893x over previous
//
#include <hip/hip_runtime.h>

#define IMG_B 256
#define IMG_H 224
#define IMG_W 224
#define HWPIX 50176
#define YP 228   // kA1 LDS row pitch in dwords (224 data + 4 pad)

// exact IEEE f32 ops, no contraction, matching numpy's elementwise semantics
#define FA(a,b) __fadd_rn((a),(b))
#define FM(a,b) __fmul_rn((a),(b))
#define FS(a,b) __fsub_rn((a),(b))
#define FD(a,b) __fdiv_rn((a),(b))

typedef float nt4 __attribute__((ext_vector_type(4)));

// python-float scalars cast to f32 exactly as numpy weak-scalar promotion does
__device__ __forceinline__ float VBF()   { return (float)(9.0/30.0*(1.9-0.1)+0.1); }
__device__ __forceinline__ float OMVBF() { return (float)(1.0 - (9.0/30.0*(1.9-0.1)+0.1)); }
__device__ __forceinline__ float VSF()   { return (float)(9.0/30.0*1.0); }

// exact blur fold (9 terms, raster order) + y1 blend, for 4 pixels
__device__ __forceinline__ void y1_from_rows(const float* yU, const float* yC,
                                             const float* yD, float* y1o) {
    const float WN = 1.0f / 13.0f, WC = 5.0f / 13.0f;
#pragma unroll
    for (int mm = 0; mm < 4; ++mm) {
        float acc = 0.0f;
        acc = FA(acc, FM(WN, yU[mm + 0]));
        acc = FA(acc, FM(WN, yU[mm + 1]));
        acc = FA(acc, FM(WN, yU[mm + 2]));
        acc = FA(acc, FM(WN, yC[mm + 0]));
        acc = FA(acc, FM(WC, yC[mm + 1]));
        acc = FA(acc, FM(WN, yC[mm + 2]));
        acc = FA(acc, FM(WN, yD[mm + 0]));
        acc = FA(acc, FM(WN, yD[mm + 1]));
        acc = FA(acc, FM(WN, yD[mm + 2]));
        y1o[mm] = FA(FM(yC[mm + 1], VBF()), FM(acc, OMVBF()));
    }
}

// prefetch raw x float4s for the 896 staged quads (rows r0-1..r0+14) into regs (kB)
__device__ __forceinline__ void stage_load(const float* __restrict__ xc, int r0,
                                           int t, float4* pf) {
#pragma unroll
    for (int u = 0; u < 4; ++u) {
        const int idx = t + 256 * u;
        float4 v = make_float4(0.f, 0.f, 0.f, 0.f);
        if (idx < 896) {
            const int row = idx / 56, c4 = (idx % 56) * 4;
            const int gi = r0 - 1 + row;
            if (gi >= 0 && gi < IMG_H)
                v = *(const float4*)(xc + (size_t)gi * IMG_W + c4);
        }
        pf[u] = v;
    }
}

// write y = s*x+m to LDS (pitch P dwords) from prefetched regs; pad rows -> 0 (kB)
__device__ __forceinline__ void stage_write(float s, float m, int r0, int t,
                                            const float4* pf, float* __restrict__ Y,
                                            int P) {
#pragma unroll
    for (int u = 0; u < 4; ++u) {
        const int idx = t + 256 * u;
        if (idx < 896) {
            const int row = idx / 56, c4 = (idx % 56) * 4;
            const int gi = r0 - 1 + row;
            float4 w;
            if (gi >= 0 && gi < IMG_H) {
                w.x = FA(FM(pf[u].x, s), m);
                w.y = FA(FM(pf[u].y, s), m);
                w.z = FA(FM(pf[u].z, s), m);
                w.w = FA(FM(pf[u].w, s), m);
            } else {
                w.x = w.y = w.z = w.w = 0.0f;
            }
            *(float4*)(&Y[row * P + c4]) = w;
        }
    }
}

// 6 y-taps from LDS (kB only; pitch 224): aligned float4 reads
__device__ __forceinline__ void lds_y6(const float* __restrict__ r, int j, float* y6) {
    const float4 vC = *(const float4*)(r + j);
    const float4 vL = *(const float4*)(r + (j > 0 ? j - 4 : 0));
    const float4 vR = *(const float4*)(r + (j + 4 < IMG_W ? j + 4 : IMG_W - 4));
    y6[0] = (j > 0) ? vL.w : 0.0f;
    y6[1] = vC.x; y6[2] = vC.y; y6[3] = vC.z; y6[4] = vC.w;
    y6[5] = (j + 4 < IMG_W) ? vR.x : 0.0f;
}

// ---- Kernel A1 (R16 structure): one block = one 3136-px chunk (14 rows) = 32
// aligned leaves. GRAY-FIRST: gray(y1) = vb*gray_y + (1-vb)*blur(gray_y).
// 12 global f4 loads/thread in flight, gray folded in regs, ONE LDS plane
// [16][YP]. One barrier, column sweep, exact chains / leaf sums / subtree root.
__global__ __launch_bounds__(256, 4) void kA1(const float* __restrict__ x,
                                              const float* __restrict__ mean_,
                                              const float* __restrict__ std_,
                                              float* __restrict__ part) {
    const int ck = blockIdx.x & 15, b = blockIdx.x >> 4;
    const int t = threadIdx.x;
    const int r0 = ck * 14;

    __shared__ float SM[3648];        // 14592 B
    float* Y  = SM;                   // [16][YP] gray plane (live: sweep)
    float* G2 = SM;                   // leaf-padded gray(y1) (after Y dies)
    float* CH = SM + 3328;
    float* LS = SM + 3584;

    // compute-phase roles: 224 active threads = 56 column-quads x 4 row-groups
    const int rg  = t / 56;
    const int col = t - rg * 56;
    const bool active = (t < 224);
    const int rcount = (rg < 2) ? 4 : 3;                      // rows 4,4,3,3
    const int rstart = (rg < 2) ? rg * 4 : 8 + (rg - 2) * 3;  // 0,4,8,11
    const int jd = col * 4;
    const bool lwave = ((t & 63) == 0)  && (col > 0);
    const bool rwave = ((t & 63) == 63) && (col < 55);

    const float s0 = std_[0], s1 = std_[1], s2 = std_[2];
    const float m0 = mean_[0], m1 = mean_[1], m2 = mean_[2];
    const float C0 = 0.299f, C1 = 0.587f, C2 = 0.114f;

    // ---- stage: all 12 loads in flight, fold to gray, one LDS plane ----
    float4 q0[4], q1[4], q2[4];
#pragma unroll
    for (int u = 0; u < 4; ++u) {
        const int idx = t + 256 * u;
        q0[u] = q1[u] = q2[u] = make_float4(0.f, 0.f, 0.f, 0.f);
        if (idx < 896) {
            const int row = idx / 56, c4 = (idx % 56) * 4;
            const int gi = r0 - 1 + row;
            if (gi >= 0 && gi < IMG_H) {
                const float* p = x + (size_t)b * 3 * HWPIX + (size_t)gi * IMG_W + c4;
                q0[u] = *(const float4*)(p);
                q1[u] = *(const float4*)(p + HWPIX);
                q2[u] = *(const float4*)(p + 2 * HWPIX);
            }
        }
    }
#define GRAY1(a0v, a1v, a2v)                                              \
    FA(FA(FM(C0, FA(FM(a0v, s0), m0)), FM(C1, FA(FM(a1v, s1), m1))),      \
       FM(C2, FA(FM(a2v, s2), m2)))
#pragma unroll
    for (int u = 0; u < 4; ++u) {
        const int idx = t + 256 * u;
        if (idx < 896) {
            const int row = idx / 56, c4 = (idx % 56) * 4;
            const int gi = r0 - 1 + row;
            float4 w = make_float4(0.f, 0.f, 0.f, 0.f);
            if (gi >= 0 && gi < IMG_H) {
                w.x = GRAY1(q0[u].x, q1[u].x, q2[u].x);
                w.y = GRAY1(q0[u].y, q1[u].y, q2[u].y);
                w.z = GRAY1(q0[u].z, q1[u].z, q2[u].z);
                w.w = GRAY1(q0[u].w, q1[u].w, q2[u].w);
            }
            *(float4*)(&Y[row * YP + c4]) = w;
        }
    }
#undef GRAY1
    __syncthreads();

    // NOTE: macro params must NOT collide with float4 member names x/y/z/w
#define LOADROW(V, LWv, RWv, yr) do {                                 \
        V   = *(const float4*)(&Y[(yr) * YP + jd]);                   \
        LWv = __shfl_up(V.w, 1, 64);                                  \
        RWv = __shfl_down(V.x, 1, 64);                                \
        if (lwave) LWv = Y[(yr) * YP + jd - 1];                       \
        if (rwave) RWv = Y[(yr) * YP + jd + 4];                       \
    } while (0)

#define FILL6(y6, V, LWv, RWv) do {                                   \
        y6[0] = (col > 0) ? LWv : 0.0f;                               \
        y6[1] = V.x; y6[2] = V.y; y6[3] = V.z; y6[4] = V.w;           \
        y6[5] = (col < 55) ? RWv : 0.0f;                              \
    } while (0)

    float4 gacc[4];

    // ---- single-channel column sweep: gacc = gray(y1) ----
    if (active) {
        float4 v0, v1, v2;
        float la0, la1, la2, ra0, ra1, ra2;
        LOADROW(v0, la0, ra0, rstart);
        LOADROW(v1, la1, ra1, rstart + 1);
#pragma unroll
        for (int k = 0; k < 4; ++k) {
            if (k < rcount) {
                LOADROW(v2, la2, ra2, rstart + k + 2);
                float yU[6], yC[6], yD[6], y1g[4];
                FILL6(yU, v0, la0, ra0);
                FILL6(yC, v1, la1, ra1);
                FILL6(yD, v2, la2, ra2);
                y1_from_rows(yU, yC, yD, y1g);
                gacc[k].x = y1g[0]; gacc[k].y = y1g[1];
                gacc[k].z = y1g[2]; gacc[k].w = y1g[3];
                v0 = v1; la0 = la1; ra0 = ra1;
                v1 = v2; la1 = la2; ra1 = ra2;
            }
        }
    }
    __syncthreads();   // Y dead -> G2 alias handoff

    // ---- write gray(y1) into leaf-padded G2 (aliases dead Y) ----
    if (active) {
#pragma unroll
        for (int k = 0; k < 4; ++k) {
            if (k < rcount) {
                const int pl = (rstart + k) * IMG_W + jd;
                const int grp = pl / 392;
                const int rem = pl - grp * 392;
                int li = rem / 96; if (li > 3) li = 3;
                const int o = rem - 96 * li;
                *(float4*)(&G2[(grp * 4 + li) * 104 + o]) = gacc[k];
            }
        }
    }
    __syncthreads();

    // ---- 8 chains per leaf (exact numpy base case) ----
    {
        const int leaf = t >> 3, e = t & 7;
        const int base = leaf * 104 + e;
        const int nk = ((leaf & 3) == 3) ? 13 : 12;
        float r = G2[base];
        for (int k = 1; k < nk; ++k) r = FA(r, G2[base + 8 * k]);
        CH[t] = r;   // t == leaf*8+e
    }
    __syncthreads();

    if (t < 32) {
        const float* c8 = &CH[t * 8];
        LS[t] = FA(FA(FA(c8[0], c8[1]), FA(c8[2], c8[3])),
                   FA(FA(c8[4], c8[5]), FA(c8[6], c8[7])));
    }
    __syncthreads();

    if (t == 0) {
        float v[32];
#pragma unroll
        for (int k = 0; k < 32; ++k) v[k] = LS[k];
        for (int n = 16; n >= 1; n >>= 1)
            for (int k = 0; k < n; ++k) v[k] = FA(v[2 * k], v[2 * k + 1]);
        part[blockIdx.x] = v[0];
    }
#undef LOADROW
#undef FILL6
}

// ---- Kernel B: one block = one 14-row chunk of one (b,c); staged. OUT is
// written with NON-TEMPORAL stores (out is never re-read; keeps x L3-resident
// so kB's and next-iter kA1's x reads stay L3-hot). Bit-exact values. ----
__global__ __launch_bounds__(256) void kB(const float* __restrict__ x,
                                          const float* __restrict__ mean_,
                                          const float* __restrict__ std_,
                                          const float* __restrict__ part,
                                          float* __restrict__ out) {
    const int ck = blockIdx.x, c = blockIdx.y, b = blockIdx.z;
    const int t = threadIdx.x;
    const int r0 = ck * 14;

    __shared__ float Y[16 * IMG_W];
    __shared__ float gsh;

    const float s = std_[c], m = mean_[c];
    float4 pf[4];
    stage_load(x + (size_t)(b * 3 + c) * HWPIX, r0, t, pf);
    stage_write(s, m, r0, t, pf, Y, IMG_W);

    if (t == 0) {
        // exact 4-level fold of the 16 chunk roots, / 50176
        float v[16];
#pragma unroll
        for (int k = 0; k < 16; ++k) v[k] = part[b * 16 + k];
#pragma unroll
        for (int n = 8; n >= 1; n >>= 1)
#pragma unroll
            for (int k = 0; k < 8; ++k)
                if (k < n) v[k] = FA(v[2 * k], v[2 * k + 1]);
        gsh = FD(v[0], 50176.0f);
    }
    __syncthreads();
    const float g = gsh;

    float* oc = out + (size_t)(b * 3 + c) * HWPIX + (size_t)r0 * IMG_W;

    for (int qi = t; qi < 784; qi += 256) {
        const int lr = qi / 56 + 1, j = (qi % 56) * 4;
        float yU[6], yC[6], yD[6], y1[4];
        lds_y6(&Y[(lr - 1) * IMG_W], j, yU);
        lds_y6(&Y[lr * IMG_W],       j, yC);
        lds_y6(&Y[(lr + 1) * IMG_W], j, yD);
        y1_from_rows(yU, yC, yD, y1);

        nt4 o4;
#pragma unroll
        for (int mm = 0; mm < 4; ++mm) {
            const float y2 = FA(FM(y1[mm], VBF()), FM(g, OMVBF()));
            const float y3 = FM(y2, VBF());
            const float y4 = (y3 < VSF()) ? y3 : FS(1.0f, y3);
            o4[mm] = FD(FS(y4, m), s);
        }
        __builtin_nontemporal_store(o4, (nt4*)(oc + (size_t)(lr - 1) * IMG_W + j));
    }
}

extern "C" void kernel_launch(void* const* d_in, const int* in_sizes, int n_in,
                              void* d_out, int out_size, void* d_ws, size_t ws_size,
                              hipStream_t stream) {
    const float* x     = (const float*)d_in[0];
    const float* mean_ = (const float*)d_in[1];
    const float* std_  = (const float*)d_in[2];
    float* out = (float*)d_out;

    float* part = (float*)d_ws;   // 4096 f32 (16 chunk roots x 256 images)

    kA1<<<IMG_B * 16, 256, 0, stream>>>(x, mean_, std_, part);

    dim3 gridB(16, 3, IMG_B);
    kB<<<gridB, 256, 0, stream>>>(x, mean_, std_, part, out);
}

// Round 19
// 77.041 us; speedup vs baseline: 1.1726x; 1.0765x over previous
//
#include <hip/hip_runtime.h>

#define IMG_B 256
#define IMG_H 224
#define IMG_W 224
#define HWPIX 50176
#define YP 228   // kA1 LDS row pitch in dwords (224 data + 4 pad)

// exact IEEE f32 ops, no contraction, matching numpy's elementwise semantics
#define FA(a,b) __fadd_rn((a),(b))
#define FM(a,b) __fmul_rn((a),(b))
#define FS(a,b) __fsub_rn((a),(b))
#define FD(a,b) __fdiv_rn((a),(b))

typedef float nt4 __attribute__((ext_vector_type(4)));

// python-float scalars cast to f32 exactly as numpy weak-scalar promotion does
__device__ __forceinline__ float VBF()   { return (float)(9.0/30.0*(1.9-0.1)+0.1); }
__device__ __forceinline__ float OMVBF() { return (float)(1.0 - (9.0/30.0*(1.9-0.1)+0.1)); }
__device__ __forceinline__ float VSF()   { return (float)(9.0/30.0*1.0); }

// exact blur fold (9 terms, raster order) + y1 blend, for 4 pixels
__device__ __forceinline__ void y1_from_rows(const float* yU, const float* yC,
                                             const float* yD, float* y1o) {
    const float WN = 1.0f / 13.0f, WC = 5.0f / 13.0f;
#pragma unroll
    for (int mm = 0; mm < 4; ++mm) {
        float acc = 0.0f;
        acc = FA(acc, FM(WN, yU[mm + 0]));
        acc = FA(acc, FM(WN, yU[mm + 1]));
        acc = FA(acc, FM(WN, yU[mm + 2]));
        acc = FA(acc, FM(WN, yC[mm + 0]));
        acc = FA(acc, FM(WC, yC[mm + 1]));
        acc = FA(acc, FM(WN, yC[mm + 2]));
        acc = FA(acc, FM(WN, yD[mm + 0]));
        acc = FA(acc, FM(WN, yD[mm + 1]));
        acc = FA(acc, FM(WN, yD[mm + 2]));
        y1o[mm] = FA(FM(yC[mm + 1], VBF()), FM(acc, OMVBF()));
    }
}

// prefetch raw x float4s for the 896 staged quads (rows r0-1..r0+14) into regs (kB)
__device__ __forceinline__ void stage_load(const float* __restrict__ xc, int r0,
                                           int t, float4* pf) {
#pragma unroll
    for (int u = 0; u < 4; ++u) {
        const int idx = t + 256 * u;
        float4 v = make_float4(0.f, 0.f, 0.f, 0.f);
        if (idx < 896) {
            const int row = idx / 56, c4 = (idx % 56) * 4;
            const int gi = r0 - 1 + row;
            if (gi >= 0 && gi < IMG_H)
                v = *(const float4*)(xc + (size_t)gi * IMG_W + c4);
        }
        pf[u] = v;
    }
}

// write y = s*x+m to LDS (pitch P dwords) from prefetched regs; pad rows -> 0 (kB)
__device__ __forceinline__ void stage_write(float s, float m, int r0, int t,
                                            const float4* pf, float* __restrict__ Y,
                                            int P) {
#pragma unroll
    for (int u = 0; u < 4; ++u) {
        const int idx = t + 256 * u;
        if (idx < 896) {
            const int row = idx / 56, c4 = (idx % 56) * 4;
            const int gi = r0 - 1 + row;
            float4 w;
            if (gi >= 0 && gi < IMG_H) {
                w.x = FA(FM(pf[u].x, s), m);
                w.y = FA(FM(pf[u].y, s), m);
                w.z = FA(FM(pf[u].z, s), m);
                w.w = FA(FM(pf[u].w, s), m);
            } else {
                w.x = w.y = w.z = w.w = 0.0f;
            }
            *(float4*)(&Y[row * P + c4]) = w;
        }
    }
}

// 6 y-taps from LDS (kB only; pitch 224): aligned float4 reads
__device__ __forceinline__ void lds_y6(const float* __restrict__ r, int j, float* y6) {
    const float4 vC = *(const float4*)(r + j);
    const float4 vL = *(const float4*)(r + (j > 0 ? j - 4 : 0));
    const float4 vR = *(const float4*)(r + (j + 4 < IMG_W ? j + 4 : IMG_W - 4));
    y6[0] = (j > 0) ? vL.w : 0.0f;
    y6[1] = vC.x; y6[2] = vC.y; y6[3] = vC.z; y6[4] = vC.w;
    y6[5] = (j + 4 < IMG_W) ? vR.x : 0.0f;
}

// ---- Kernel A1 (R16 structure + XCD swizzle): one block = one 3136-px chunk
// (14 rows) = 32 aligned leaves. GRAY-FIRST. 12 global f4 loads/thread in
// flight, gray folded in regs, ONE LDS plane [16][YP]. One barrier, column
// sweep, exact chains / leaf sums / subtree root.
__global__ __launch_bounds__(256, 4) void kA1(const float* __restrict__ x,
                                              const float* __restrict__ mean_,
                                              const float* __restrict__ std_,
                                              float* __restrict__ part) {
    // bijective XCD swizzle (4096 % 8 == 0): each XCD gets 32 whole images ->
    // an image's 16 chunks share one XCD's L2 (halo-row reuse).
    const int swz = (blockIdx.x & 7) * 512 + (blockIdx.x >> 3);
    const int ck = swz & 15, b = swz >> 4;
    const int t = threadIdx.x;
    const int r0 = ck * 14;

    __shared__ float SM[3648];        // 14592 B
    float* Y  = SM;                   // [16][YP] gray plane (live: sweep)
    float* G2 = SM;                   // leaf-padded gray(y1) (after Y dies)
    float* CH = SM + 3328;
    float* LS = SM + 3584;

    // compute-phase roles: 224 active threads = 56 column-quads x 4 row-groups
    const int rg  = t / 56;
    const int col = t - rg * 56;
    const bool active = (t < 224);
    const int rcount = (rg < 2) ? 4 : 3;                      // rows 4,4,3,3
    const int rstart = (rg < 2) ? rg * 4 : 8 + (rg - 2) * 3;  // 0,4,8,11
    const int jd = col * 4;
    const bool lwave = ((t & 63) == 0)  && (col > 0);
    const bool rwave = ((t & 63) == 63) && (col < 55);

    const float s0 = std_[0], s1 = std_[1], s2 = std_[2];
    const float m0 = mean_[0], m1 = mean_[1], m2 = mean_[2];
    const float C0 = 0.299f, C1 = 0.587f, C2 = 0.114f;

    // ---- stage: all 12 loads in flight, fold to gray, one LDS plane ----
    float4 q0[4], q1[4], q2[4];
#pragma unroll
    for (int u = 0; u < 4; ++u) {
        const int idx = t + 256 * u;
        q0[u] = q1[u] = q2[u] = make_float4(0.f, 0.f, 0.f, 0.f);
        if (idx < 896) {
            const int row = idx / 56, c4 = (idx % 56) * 4;
            const int gi = r0 - 1 + row;
            if (gi >= 0 && gi < IMG_H) {
                const float* p = x + (size_t)b * 3 * HWPIX + (size_t)gi * IMG_W + c4;
                q0[u] = *(const float4*)(p);
                q1[u] = *(const float4*)(p + HWPIX);
                q2[u] = *(const float4*)(p + 2 * HWPIX);
            }
        }
    }
#define GRAY1(a0v, a1v, a2v)                                              \
    FA(FA(FM(C0, FA(FM(a0v, s0), m0)), FM(C1, FA(FM(a1v, s1), m1))),      \
       FM(C2, FA(FM(a2v, s2), m2)))
#pragma unroll
    for (int u = 0; u < 4; ++u) {
        const int idx = t + 256 * u;
        if (idx < 896) {
            const int row = idx / 56, c4 = (idx % 56) * 4;
            const int gi = r0 - 1 + row;
            float4 w = make_float4(0.f, 0.f, 0.f, 0.f);
            if (gi >= 0 && gi < IMG_H) {
                w.x = GRAY1(q0[u].x, q1[u].x, q2[u].x);
                w.y = GRAY1(q0[u].y, q1[u].y, q2[u].y);
                w.z = GRAY1(q0[u].z, q1[u].z, q2[u].z);
                w.w = GRAY1(q0[u].w, q1[u].w, q2[u].w);
            }
            *(float4*)(&Y[row * YP + c4]) = w;
        }
    }
#undef GRAY1
    __syncthreads();

    // NOTE: macro params must NOT collide with float4 member names x/y/z/w
#define LOADROW(V, LWv, RWv, yr) do {                                 \
        V   = *(const float4*)(&Y[(yr) * YP + jd]);                   \
        LWv = __shfl_up(V.w, 1, 64);                                  \
        RWv = __shfl_down(V.x, 1, 64);                                \
        if (lwave) LWv = Y[(yr) * YP + jd - 1];                       \
        if (rwave) RWv = Y[(yr) * YP + jd + 4];                       \
    } while (0)

#define FILL6(y6, V, LWv, RWv) do {                                   \
        y6[0] = (col > 0) ? LWv : 0.0f;                               \
        y6[1] = V.x; y6[2] = V.y; y6[3] = V.z; y6[4] = V.w;           \
        y6[5] = (col < 55) ? RWv : 0.0f;                              \
    } while (0)

    float4 gacc[4];

    // ---- single-channel column sweep: gacc = gray(y1) ----
    if (active) {
        float4 v0, v1, v2;
        float la0, la1, la2, ra0, ra1, ra2;
        LOADROW(v0, la0, ra0, rstart);
        LOADROW(v1, la1, ra1, rstart + 1);
#pragma unroll
        for (int k = 0; k < 4; ++k) {
            if (k < rcount) {
                LOADROW(v2, la2, ra2, rstart + k + 2);
                float yU[6], yC[6], yD[6], y1g[4];
                FILL6(yU, v0, la0, ra0);
                FILL6(yC, v1, la1, ra1);
                FILL6(yD, v2, la2, ra2);
                y1_from_rows(yU, yC, yD, y1g);
                gacc[k].x = y1g[0]; gacc[k].y = y1g[1];
                gacc[k].z = y1g[2]; gacc[k].w = y1g[3];
                v0 = v1; la0 = la1; ra0 = ra1;
                v1 = v2; la1 = la2; ra1 = ra2;
            }
        }
    }
    __syncthreads();   // Y dead -> G2 alias handoff

    // ---- write gray(y1) into leaf-padded G2 (aliases dead Y) ----
    if (active) {
#pragma unroll
        for (int k = 0; k < 4; ++k) {
            if (k < rcount) {
                const int pl = (rstart + k) * IMG_W + jd;
                const int grp = pl / 392;
                const int rem = pl - grp * 392;
                int li = rem / 96; if (li > 3) li = 3;
                const int o = rem - 96 * li;
                *(float4*)(&G2[(grp * 4 + li) * 104 + o]) = gacc[k];
            }
        }
    }
    __syncthreads();

    // ---- 8 chains per leaf (exact numpy base case) ----
    {
        const int leaf = t >> 3, e = t & 7;
        const int base = leaf * 104 + e;
        const int nk = ((leaf & 3) == 3) ? 13 : 12;
        float r = G2[base];
        for (int k = 1; k < nk; ++k) r = FA(r, G2[base + 8 * k]);
        CH[t] = r;   // t == leaf*8+e
    }
    __syncthreads();

    if (t < 32) {
        const float* c8 = &CH[t * 8];
        LS[t] = FA(FA(FA(c8[0], c8[1]), FA(c8[2], c8[3])),
                   FA(FA(c8[4], c8[5]), FA(c8[6], c8[7])));
    }
    __syncthreads();

    if (t == 0) {
        float v[32];
#pragma unroll
        for (int k = 0; k < 32; ++k) v[k] = LS[k];
        for (int n = 16; n >= 1; n >>= 1)
            for (int k = 0; k < n; ++k) v[k] = FA(v[2 * k], v[2 * k + 1]);
        part[swz] = v[0];
    }
#undef LOADROW
#undef FILL6
}

// ---- Kernel B: 1-D grid (12288 blocks) with the same XCD swizzle; one block
// = one 14-row chunk of one (b,c). gm fold hoisted BEFORE stage_write so the
// 16 part[] loads overlap the big x-load latency. NT stores for out. ----
__global__ __launch_bounds__(256) void kB(const float* __restrict__ x,
                                          const float* __restrict__ mean_,
                                          const float* __restrict__ std_,
                                          const float* __restrict__ part,
                                          float* __restrict__ out) {
    // bijective XCD swizzle (12288 % 8 == 0): contiguous (ck,c,b) ranges per
    // XCD -> adjacent chunks' halo rows reuse the same L2.
    const int swz = ((int)blockIdx.x & 7) * 1536 + ((int)blockIdx.x >> 3);
    const int ck = swz & 15;
    const int r1 = swz >> 4;
    const int c  = r1 % 3;
    const int b  = r1 / 3;
    const int t  = threadIdx.x;
    const int r0 = ck * 14;

    __shared__ float Y[16 * IMG_W];
    __shared__ float gsh;

    const float s = std_[c], m = mean_[c];
    float4 pf[4];
    stage_load(x + (size_t)(b * 3 + c) * HWPIX, r0, t, pf);

    if (t == 0) {
        // exact 4-level fold of the 16 chunk roots, / 50176
        // (issued while the x stage loads are still in flight)
        float v[16];
#pragma unroll
        for (int k = 0; k < 16; ++k) v[k] = part[b * 16 + k];
#pragma unroll
        for (int n = 8; n >= 1; n >>= 1)
#pragma unroll
            for (int k = 0; k < 8; ++k)
                if (k < n) v[k] = FA(v[2 * k], v[2 * k + 1]);
        gsh = FD(v[0], 50176.0f);
    }

    stage_write(s, m, r0, t, pf, Y, IMG_W);
    __syncthreads();
    const float g = gsh;

    float* oc = out + (size_t)(b * 3 + c) * HWPIX + (size_t)r0 * IMG_W;

    for (int qi = t; qi < 784; qi += 256) {
        const int lr = qi / 56 + 1, j = (qi % 56) * 4;
        float yU[6], yC[6], yD[6], y1[4];
        lds_y6(&Y[(lr - 1) * IMG_W], j, yU);
        lds_y6(&Y[lr * IMG_W],       j, yC);
        lds_y6(&Y[(lr + 1) * IMG_W], j, yD);
        y1_from_rows(yU, yC, yD, y1);

        nt4 o4;
#pragma unroll
        for (int mm = 0; mm < 4; ++mm) {
            const float y2 = FA(FM(y1[mm], VBF()), FM(g, OMVBF()));
            const float y3 = FM(y2, VBF());
            const float y4 = (y3 < VSF()) ? y3 : FS(1.0f, y3);
            o4[mm] = FD(FS(y4, m), s);
        }
        __builtin_nontemporal_store(o4, (nt4*)(oc + (size_t)(lr - 1) * IMG_W + j));
    }
}

extern "C" void kernel_launch(void* const* d_in, const int* in_sizes, int n_in,
                              void* d_out, int out_size, void* d_ws, size_t ws_size,
                              hipStream_t stream) {
    const float* x     = (const float*)d_in[0];
    const float* mean_ = (const float*)d_in[1];
    const float* std_  = (const float*)d_in[2];
    float* out = (float*)d_out;

    float* part = (float*)d_ws;   // 4096 f32 (16 chunk roots x 256 images)

    kA1<<<IMG_B * 16, 256, 0, stream>>>(x, mean_, std_, part);

    kB<<<IMG_B * 3 * 16, 256, 0, stream>>>(x, mean_, std_, part, out);
}